// Round 8
// baseline (2110.587 us; speedup 1.0000x reference)
//
#include <hip/hip_runtime.h>

// Problem constants (SIZE=68, SSN=8 -> C=9, S1=69, BATCH=256)
#define C9     9
#define S1     69
#define JT     621            // C9*S1: one (class,pos) plane
#define NBATCH 256
#define NSTEP  68
#define QJ     4761           // 69*69   (Q j-stride, P s-major plane size)
#define QI     42849          // 9*69*69 (Q i-stride; also P batch stride)
#define BROW   42849          // 69 planes * 621 per-batch alpha
#define ALPHA_N (NBATCH*BROW)
#define QTFL   385664         // padded float count of one ws region
#define NEGINF (-__builtin_inff())

// Vector type with 4-byte alignment guarantee (rows have odd stride 69).
typedef float float2u __attribute__((ext_vector_type(2), aligned(4)));

// LDS-only barrier: __syncthreads() compiles to s_waitcnt vmcnt(0)
// lgkmcnt(0) + s_barrier, draining the global-load pipeline twice per step.
// The scan's barriers only order LDS (part/red/la); the Q/P prefetch stream
// and alpha stores may legally stay in flight.  (T3/T4 pattern; rule #18
// sched_barrier guard.)
__device__ __forceinline__ void barrier_lgkm()
{
  __builtin_amdgcn_sched_barrier(0);
  asm volatile("s_waitcnt lgkmcnt(0)" ::: "memory");
  __builtin_amdgcn_s_barrier();
  __builtin_amdgcn_sched_barrier(0);
}

// ---------------------------------------------------------------------------
// qw: QW[j][s][i][t] = Q[j][i][s][t].  9 i-values at stride 276 B from one
// base; s-advance = one pointer bump in the scan inner loop.
__global__ void qw_kernel(const float* __restrict__ Q, float* __restrict__ QW)
{
  const int bl = blockIdx.x;           // j*69 + s
  const int j = bl / S1, s = bl - j*S1;
  float* dst = QW + (size_t)bl*JT;
  const float* src = Q + (size_t)j*QJ + s*S1;
  for (int f = threadIdx.x; f < JT; f += 256){
    const int i = f / S1, t = f - i*S1;
    dst[f] = src[i*QJ + t];
  }
}

// ---------------------------------------------------------------------------
// qtrans: QT[c][t][i][s] = Q[c][i][s][t]  (coalesced backtrace Q reads)
__global__ void qtrans_kernel(const float* __restrict__ Q, float* __restrict__ QT)
{
  __shared__ float tile[69*70];
  const int pl = blockIdx.x;           // c*9 + i
  const int c = pl / 9, i = pl - c*9;
  const float* src = Q + (size_t)pl*QJ;
  for (int f = threadIdx.x; f < QJ; f += 256){
    const int s = f / S1, t = f - s*S1;
    tile[s*70 + t] = src[f];
  }
  __syncthreads();
  float* dst = QT + (size_t)c*QI + i*S1;     // + t*621 + s
  for (int f = threadIdx.x; f < QJ; f += 256){
    const int t = f / S1, s = f - t*S1;
    dst[t*JT + s] = tile[s*70 + t];
  }
}

// ---------------------------------------------------------------------------
// mega v8: one batch per block, grid 256, 704 threads = 11 waves (the
// 704-thread shape gets a ~84-VGPR budget vs 64 at 1024 -- measured r2/r7).
// 2 s-groups x 315 (j,t-pair) slots, s-ranges {0-34},{34-68} (overlap row
// duplicated -- max idempotent, exact).  KEY CHANGE vs r7: the Q/P load
// stream is IDENTICAL every step (only la changes), so the load ping-pong
// is carried ACROSS the step boundary (last load of step k prefetches s0
// for step k+1) and the two per-step barriers are LDS-only raw barriers --
// no vmcnt(0) drain, no per-step pipeline cold-start.
__global__ __launch_bounds__(704) void mega_kernel(
    const float* __restrict__ P, const float* __restrict__ Q,
    const float* __restrict__ pi, const float* __restrict__ Tp,
    const int* __restrict__ ls, float* __restrict__ out,
    const float* __restrict__ QW, const float* __restrict__ QT, int wsmode)
{
  __shared__ __align__(16) float la[2][C9*72];   // la[buf][i*72 + s]
  __shared__ float part[315][3];                 // g1 partials (stride 3)
  __shared__ float red[11];
  __shared__ float m_sh[NSTEP+1], lse_sh[NSTEP+1], n_sh[NSTEP+1];
  __shared__ float sums_sh[NSTEP+1][5];          // per-(k, g0-wave) exp sums
  __shared__ float sbest[11];
  __shared__ int   sidx[11];
  __shared__ int   sct[2];

  const int tid  = threadIdx.x;
  const int w    = tid >> 6;
  const int lane = tid & 63;
  const int b    = blockIdx.x;
  const bool act = tid < 630;
  const int gg   = act ? tid / 315 : 1;          // s-group 0..1
  const int slot = act ? tid - gg*315 : 314;
  const int j    = slot / 35;                    // output class 0..8
  const int tp   = slot - j*35;                  // t-pair 0..34
  const bool own2 = (tp < 34);
  const int t0   = own2 ? 2*tp : 67;             // tp=34: clamp, owns only t=68
  const int s_lo = gg*34;                        // {0,34}; width 35 each
  const float Tv = Tp[0];

  float* outb = out + (size_t)b*BROW;

  // ---- prep: v[0] raw (pi at s==0, else -inf); m[0], lse_v[0] ----
  for (int e = tid; e < JT; e += 704){
    const int i = e / S1, s = e - i*S1;
    const float v0i = (s == 0) ? pi[i] : NEGINF;
    outb[68*JT + e] = v0i;
    la[0][i*72 + s] = v0i;
  }
  if (tid == 0){
    float mx = pi[0];
    #pragma unroll
    for (int c = 1; c < C9; ++c) mx = fmaxf(mx, pi[c]);
    float sm = 0.f;
    #pragma unroll
    for (int c = 0; c < C9; ++c) sm += expf(pi[c] - mx);
    m_sh[0]   = mx;
    lse_sh[0] = mx + logf(sm);
  }
  __syncthreads();
  float mprev = m_sh[0];

  const bool useQW = (wsmode >= 1);
  // QW[j][s][i][t]: s-stride JT, i-stride S1.  Raw Q: s-stride S1, i-stride QI.
  const float* qb = useQW ? (QW + (size_t)j*QI + (size_t)s_lo*JT + t0)
                          : (Q  + (size_t)j*QJ + s_lo*S1 + t0);
  const float* pb = P + (size_t)(b*C9 + j)*QJ + s_lo*S1 + t0;
  float* la0 = la[0];
  float* la1 = la[1];

#define LDQ(B, PTR, SI) { \
  _Pragma("unroll") \
  for (int i_ = 0; i_ < C9; ++i_) B[i_] = *(const float2u*)((PTR) + i_*(SI)); }

#define CMQ(B, PPTR, LC, IDX) { \
  const float2u pv_ = *(const float2u*)(PPTR); \
  float r0 = NEGINF, r1 = NEGINF; \
  _Pragma("unroll") \
  for (int i_ = 0; i_ < C9; ++i_){ \
    const float lv_ = (LC)[i_*72 + (IDX)]; \
    r0 = fmaxf(r0, fmaf(Tv, B[i_].x, lv_)); \
    r1 = fmaxf(r1, fmaf(Tv, B[i_].y, lv_)); \
  } \
  acc.x = fmaxf(acc.x, pv_.x + r0); \
  acc.y = fmaxf(acc.y, pv_.y + r1); }

// One scan step.  Entering: BE holds this step's s-row 0.  Exiting: BO holds
// NEXT step's s-row 0 (prefetched before the last compute -- the barrier /
// reduction section below becomes its latency cover).
#define STEP(K, BE, BO, LAR, LAW, SI, SS) { \
  float2u acc; acc.x = acc.y = NEGINF; \
  if (act){ \
    const float* qc = qb + (SS); \
    const float* pc = pb; \
    const float* lc = (LAR) + s_lo; \
    for (int p_ = 0; p_ < 17; ++p_){ \
      LDQ(BO, qc, SI) \
      CMQ(BE, pc, lc, 0) \
      LDQ(BE, qc + (SS), SI) \
      CMQ(BO, pc + S1, lc, 1) \
      qc += 2*(SS); pc += 2*S1; lc += 2; \
    } \
    LDQ(BO, qb, SI)                       /* next-step s0 prefetch */ \
    CMQ(BE, pc, lc, 0)                    /* idx 34 */ \
    if (gg == 1){ part[slot][0] = acc.x; part[slot][1] = acc.y; } \
  } \
  barrier_lgkm();                         /* (A) partials ready */ \
  float mval = NEGINF; float v0 = 0.f, v1 = 0.f; \
  if (act && gg == 0){ \
    const float c0 = fmaxf(acc.x, part[slot][0]); \
    const float c1 = fmaxf(acc.y, part[slot][1]); \
    v0 = c0 - mprev; v1 = c1 - mprev; \
    float* dst = outb + (size_t)(68-(K))*JT + j*S1 + t0; \
    if (own2){ \
      float2u vv; vv.x = v0; vv.y = v1; \
      *(float2u*)dst = vv; \
      (LAW)[j*72 + t0]     = v0; \
      (LAW)[j*72 + t0 + 1] = v1; \
      mval = fmaxf(v0, v1); \
    } else { \
      dst[1] = v1; \
      (LAW)[j*72 + 68] = v1; \
      mval = v1; \
    } \
  } \
  float mr = mval; \
  _Pragma("unroll") \
  for (int o_ = 32; o_ >= 1; o_ >>= 1) mr = fmaxf(mr, __shfl_down(mr, o_)); \
  if (lane == 0) red[w] = mr; \
  barrier_lgkm();                         /* (B) red + la ready */ \
  float mA = red[0]; \
  _Pragma("unroll") \
  for (int q_ = 1; q_ < 5; ++q_) mA = fmaxf(mA, red[q_]); \
  float sv = 0.f; \
  if (act && gg == 0) \
    sv = own2 ? (expf(v0 - mA) + expf(v1 - mA)) : expf(v1 - mA); \
  _Pragma("unroll") \
  for (int o_ = 32; o_ >= 1; o_ >>= 1) sv += __shfl_down(sv, o_); \
  if (lane == 0 && w < 5) sums_sh[K][w] = sv; \
  if (tid == 0) m_sh[K] = mA; \
  mprev = mA; }

#define KLOOP(SI, SS) { \
  float2u qE[C9], qO[C9]; \
  if (act) LDQ(qE, qb, SI) \
  for (int kk = 1; kk <= NSTEP; kk += 2){ \
    STEP(kk,   qE, qO, la0, la1, SI, SS) \
    STEP(kk+1, qO, qE, la1, la0, SI, SS) \
  } }

  // ---- 68 max-plus steps (cross-step pipelined) ----
  if (useQW){ KLOOP(S1, JT) }
  else      { KLOOP(QI, S1) }

  __syncthreads();   // full drain: alpha stores + LDS visible to all

  // ---- lse finalize + n[k] = lse_v[k] + D[k], D[k]=sum_{kk<k} m (double) ----
  if (tid == 0){
    double dd = 0.0;
    for (int kk = 0; kk <= NSTEP; ++kk){
      float lse;
      if (kk == 0) lse = lse_sh[0];
      else {
        float S = sums_sh[kk][0];
        #pragma unroll
        for (int q = 1; q < 5; ++q) S += sums_sh[kk][q];
        lse = m_sh[kk] + logf(S);
      }
      lse_sh[kk] = lse;
      n_sh[kk] = (float)((double)lse + dd);
      dd += (double)m_sh[kk];
    }
  }
  __syncthreads();

  // ---- addc: alpha[K] = v[68-K] + (n[K] - lse_v[68-K]), clamp -3e38 ----
  for (int K = 0; K <= NSTEP; ++K){
    const float Cst = n_sh[K] - lse_sh[68-K];
    for (int e = tid; e < JT; e += 704){
      float* r = outb + (size_t)K*JT + e;
      *r = fmaxf(*r + Cst, -3.0e38f);
    }
  }
  __syncthreads();

  // ---- backtrace: 621 candidates, one per thread ----
  {
    int c = 3, t2 = ls[b];
    float* mpb = out + (size_t)ALPHA_N + (size_t)b*(69*3);
    if (tid == 0){
      mpb[68*3+0] = 3.f; mpb[68*3+1] = 0.f; mpb[68*3+2] = (float)t2;
      mpb[67*3+1] = 0.f;   // l_0 = 0 after the shift
    }
    const bool vok = tid < JT;
    const int etid = vok ? tid : 0;
    const int im = etid / S1;
    const int sm = etid - im*S1;
    float av = vok ? outb[1*JT + tid] : NEGINF;
    for (int r = 1; r <= NSTEP; ++r){
      float avn = NEGINF;
      if (r < NSTEP && vok) avn = outb[(size_t)(r+1)*JT + tid];
      float best = NEGINF; int bidx = 0x7fffffff;
      if (vok){
        float qv;
        if (wsmode >= 2)      qv = QT[(size_t)c*QI + (size_t)t2*JT + tid];
        else if (wsmode == 1) qv = QW[(size_t)c*QI + (size_t)sm*JT + im*S1 + t2];
        else                  qv = Q[(size_t)c*QI + (size_t)im*QJ + sm*S1 + t2];
        const float pv = P[(size_t)(b*C9 + c)*QJ + sm*S1 + t2];
        best = (pv + Tv*qv) + av;   // exact ref association
        bidx = tid;
      }
      // argmax: strict > with min-index tie-break == jnp.argmax first-occurrence
      #pragma unroll
      for (int o = 32; o >= 1; o >>= 1){
        const float ov = __shfl_down(best, o); const int oi = __shfl_down(bidx, o);
        if (ov > best || (ov == best && oi < bidx)){ best = ov; bidx = oi; }
      }
      if (lane == 0){ sbest[w] = best; sidx[w] = bidx; }
      __syncthreads();
      if (tid == 0){
        float bb = sbest[0]; int bi = sidx[0];
        #pragma unroll
        for (int q = 1; q < 11; ++q)
          if (sbest[q] > bb || (sbest[q] == bb && sidx[q] < bi)){
            bb = sbest[q]; bi = sidx[q];
          }
        const int cn = bi / S1, tn = bi - cn*S1;
        mpb[(68-r)*3 + 0] = (float)cn;
        mpb[(68-r)*3 + 2] = (float)tn;
        if (r <= 67) mpb[(67-r)*3 + 1] = (float)(tn - t2);
        sct[0] = cn; sct[1] = tn;
      }
      __syncthreads();
      c = sct[0]; t2 = sct[1];
      av = avn;
    }
  }
}

// ---------------------------------------------------------------------------
extern "C" void kernel_launch(void* const* d_in, const int* in_sizes, int n_in,
                              void* d_out, int out_size, void* d_ws, size_t ws_size,
                              hipStream_t stream)
{
  const float* P  = (const float*)d_in[0];
  const float* Q  = (const float*)d_in[1];
  const float* pi = (const float*)d_in[2];
  const float* T  = (const float*)d_in[3];
  const int*   ls = (const int*)d_in[4];

  float* out = (float*)d_out;

  // ws regions (launch-invariant branches -> graph-safe):
  //   [0, QTFL)        QW  (scan-optimized Q layout)
  //   [QTFL, 2*QTFL)   QT  (backtrace-coalesced Q layout)
  int wsmode = 0; float* QW = nullptr; float* QT = nullptr;
  if (ws_size >= (size_t)QTFL*4){ wsmode = 1; QW = (float*)d_ws; }
  if (ws_size >= (size_t)2*QTFL*4){ wsmode = 2; QT = (float*)d_ws + QTFL; }

  if (wsmode >= 1) qw_kernel<<<JT, 256, 0, stream>>>(Q, QW);
  if (wsmode >= 2) qtrans_kernel<<<81, 256, 0, stream>>>(Q, QT);
  mega_kernel<<<NBATCH, 704, 0, stream>>>(P, Q, pi, T, ls, out, QW, QT, wsmode);
}